// Round 3
// baseline (86807.990 us; speedup 1.0000x reference)
//
#include <hip/hip_runtime.h>
#include <hip/hip_cooperative_groups.h>
#include <math.h>

namespace cg = cooperative_groups;

// ---------------- problem dims ----------------
#define T_STEPS 512
#define BATCH   128
#define DIN     256
#define HMAIN   1024
#define HHYP    256
#define OUTN    128
#define EPS     1e-3f

#define KSPLIT_NONE (1<<30)

typedef __attribute__((ext_vector_type(4))) float f32x4;
typedef __attribute__((ext_vector_type(8))) short s16x8;

__device__ __forceinline__ float sigm(float x){ return 1.f/(1.f + expf(-x)); }

__device__ __forceinline__ unsigned short f2bf(float f){
    union { float f; unsigned u; } x; x.f = f;
    unsigned r = x.u + 0x7FFFu + ((x.u >> 16) & 1u);   // RNE
    return (unsigned short)(r >> 16);
}

// =====================================================================
// fp32 tiled GEMM (prep only): tile 32x64, KT=32, 128 thr, 4x4 micro
// =====================================================================
#define BM 32
#define BN 64
#define KT 32
__device__ void gemm_dev(const float* __restrict__ A1, int lda1, int ksplit,
                         const float* __restrict__ A2, int lda2,
                         const float* __restrict__ Bp, int ldb, int b_nk,
                         const float* __restrict__ bias,
                         float* __restrict__ C, int ldc,
                         int K, int k0, int mtile, int ntile)
{
    __shared__ __align__(16) float As[KT][BM+4];
    __shared__ __align__(16) float Bs[KT][BN+4];
    const int tid = threadIdx.x;
    const int mt = tid >> 4, nt = tid & 15;
    const int m0g = mtile*BM, n0g = ntile*BN;
    float acc[4][4];
    #pragma unroll
    for (int i=0;i<4;++i) { acc[i][0]=0;acc[i][1]=0;acc[i][2]=0;acc[i][3]=0; }
    for (int kt = 0; kt < K; kt += KT) {
        __syncthreads();
        #pragma unroll
        for (int i=0;i<8;++i){
            int e = tid + i*128;
            int m = e >> 5, k = e & 31;
            int gk = k0 + kt + k, gm = m0g + m;
            float v = (gk < ksplit) ? A1[(size_t)gm*lda1 + gk]
                                    : A2[(size_t)gm*lda2 + (gk - ksplit)];
            As[k][m] = v;
        }
        if (b_nk) {
            #pragma unroll
            for (int i=0;i<16;++i){
                int e = tid + i*128;
                int n = e >> 5, k = e & 31;
                Bs[k][n] = Bp[(size_t)(n0g + n)*ldb + (k0 + kt + k)];
            }
        } else {
            #pragma unroll
            for (int i=0;i<16;++i){
                int e = tid + i*128;
                int k = e >> 6, n = e & 63;
                Bs[k][n] = Bp[(size_t)(k0 + kt + k)*ldb + (n0g + n)];
            }
        }
        __syncthreads();
        #pragma unroll
        for (int k=0;k<KT;++k){
            float4 av = *(const float4*)(&As[k][4*mt]);
            float4 bv = *(const float4*)(&Bs[k][4*nt]);
            acc[0][0]+=av.x*bv.x; acc[0][1]+=av.x*bv.y; acc[0][2]+=av.x*bv.z; acc[0][3]+=av.x*bv.w;
            acc[1][0]+=av.y*bv.x; acc[1][1]+=av.y*bv.y; acc[1][2]+=av.y*bv.z; acc[1][3]+=av.y*bv.w;
            acc[2][0]+=av.z*bv.x; acc[2][1]+=av.z*bv.y; acc[2][2]+=av.z*bv.z; acc[2][3]+=av.z*bv.w;
            acc[3][0]+=av.w*bv.x; acc[3][1]+=av.w*bv.y; acc[3][2]+=av.w*bv.z; acc[3][3]+=av.w*bv.w;
        }
    }
    #pragma unroll
    for (int i=0;i<4;++i){
        int gm = m0g + 4*mt + i;
        #pragma unroll
        for (int j=0;j<4;++j){
            int gn = n0g + 4*nt + j;
            float v = acc[i][j];
            if (bias) v += bias[gn];
            C[(size_t)gm*ldc + gn] = v;
        }
    }
}

// =====================================================================
// bf16 MFMA GEMM: block tile 32(M) x 128(N), KT=32, 256 thr (4 waves)
// =====================================================================
#define ASTR 40
__device__ void gemm_mfma(const float* __restrict__ A1, int lda1, int ksplit,
                          const float* __restrict__ A2, int lda2,
                          const unsigned short* __restrict__ B, int ldb,
                          const float* __restrict__ bias,
                          float* __restrict__ C, int ldc,
                          int K, int k0, int mtile, int ntile)
{
    __shared__ __align__(16) unsigned short As[32*ASTR];
    __shared__ __align__(16) unsigned short Bs[128*ASTR];
    const int tid = threadIdx.x;
    const int lane = tid & 63, w = tid >> 6;
    const int wm = (w >> 1) * 16, wn = (w & 1) * 64;
    const int fr = lane & 15, koff = (lane >> 4) * 8;
    const int m0g = mtile*32, n0g = ntile*128;

    f32x4 acc[4];
    #pragma unroll
    for (int j=0;j<4;++j) acc[j] = (f32x4){0.f,0.f,0.f,0.f};

    const int arow = tid >> 3, akc = (tid & 7) * 4;
    for (int kt = 0; kt < K; kt += 32) {
        __syncthreads();
        {
            int gk = k0 + kt + akc;
            int gm = m0g + arow;
            const float* src = (gk < ksplit) ? (A1 + (size_t)gm*lda1 + gk)
                                             : (A2 + (size_t)gm*lda2 + (gk - ksplit));
            float4 v = *(const float4*)src;
            unsigned short* d = &As[arow*ASTR + akc];
            d[0] = f2bf(v.x); d[1] = f2bf(v.y); d[2] = f2bf(v.z); d[3] = f2bf(v.w);
        }
        #pragma unroll
        for (int i=0;i<4;++i){
            int e = tid + i*256;
            int n = e >> 3, kc = (e & 7) * 4;
            ushort4 bv = *(const ushort4*)(B + (size_t)(n0g + n)*ldb + (k0 + kt + kc));
            unsigned short* d = &Bs[n*ASTR + kc];
            d[0] = bv.x; d[1] = bv.y; d[2] = bv.z; d[3] = bv.w;
        }
        __syncthreads();
        s16x8 af = *(const s16x8*)&As[(wm + fr)*ASTR + koff];
        #pragma unroll
        for (int j=0;j<4;++j){
            s16x8 bf = *(const s16x8*)&Bs[(wn + j*16 + fr)*ASTR + koff];
            acc[j] = __builtin_amdgcn_mfma_f32_16x16x32_bf16(af, bf, acc[j], 0, 0, 0);
        }
    }
    #pragma unroll
    for (int j=0;j<4;++j){
        int gn = n0g + wn + j*16 + fr;
        float bb = bias ? bias[gn] : 0.f;
        #pragma unroll
        for (int r=0;r<4;++r){
            int gm = m0g + wm + (lane >> 4)*4 + r;
            C[(size_t)gm*ldc + gn] = acc[j][r] + bb;
        }
    }
}

// =====================================================================
// prep kernels (unchanged from round 2)
// =====================================================================
__global__ __launch_bounds__(256) void k_prep_convert(
    const float* __restrict__ hyp_Wx, const float* __restrict__ hyp_Wh,
    const float* __restrict__ hyp_bx, const float* __restrict__ hyp_bh,
    const float* __restrict__ Wx, const float* __restrict__ Wh,
    unsigned short* __restrict__ wcat1bf, unsigned short* __restrict__ wxbf,
    unsigned short* __restrict__ whbf, float* __restrict__ bias1,
    float* __restrict__ act1, float* __restrict__ c, float* __restrict__ ch)
{
    size_t i = (size_t)blockIdx.x*256 + threadIdx.x;
    if (i < 1572864u) {
        int n = (int)(i / 1536), k = (int)(i % 1536);
        float v = (k < 1280) ? hyp_Wx[(size_t)n*1280 + k] : hyp_Wh[(size_t)n*256 + (k-1280)];
        wcat1bf[i] = f2bf(v); return;
    }
    i -= 1572864u;
    if (i < 1048576u) { wxbf[i] = f2bf(Wx[i]); return; }
    i -= 1048576u;
    if (i < 4194304u) { whbf[i] = f2bf(Wh[i]); return; }
    i -= 4194304u;
    if (i < 1024u) { bias1[i] = hyp_bx[i] + hyp_bh[i]; return; }
    i -= 1024u;
    if (i < 163840u) { act1[i] = 0.f; return; }
    i -= 163840u;
    if (i < 131072u) { c[i] = 0.f; return; }
    i -= 131072u;
    if (i < 32768u) { ch[i] = 0.f; return; }
}

__global__ __launch_bounds__(128) void k_prep_wcomb(
    const float* __restrict__ zw_w, const float* __restrict__ zb,
    const float* __restrict__ alpha, const float* __restrict__ zbeta,
    float* __restrict__ wcombf32)
{
    int kk = blockIdx.z;
    const float* A = (kk < 8) ? (zw_w + (size_t)kk*65536) : (zb + (size_t)(kk-8)*65536);
    const float* Bm = (kk < 8) ? (alpha + (size_t)kk*262144) : (zbeta + (size_t)(kk-8)*262144);
    gemm_dev(A, 256, KSPLIT_NONE, A, 256, Bm, 1024, 0, nullptr,
             wcombf32 + (size_t)kk*262144, 1024, 256, 0, blockIdx.x, blockIdx.y);
}

__global__ __launch_bounds__(256) void k_prep_cvtcomb(
    const float* __restrict__ wcombf32, unsigned short* __restrict__ wcombbf)
{
    size_t i = (size_t)blockIdx.x*256 + threadIdx.x;
    if (i >= 3145728u) return;
    int kk = (int)(i / 262144u);
    int r  = (int)(i % 262144u);
    int n = r / 256, k = r % 256;
    wcombbf[i] = f2bf(wcombf32[(size_t)kk*262144 + (size_t)k*1024 + n]);
}

__global__ __launch_bounds__(256) void k_prep_bcomb(
    const float* __restrict__ zw_b, const float* __restrict__ alpha,
    float* __restrict__ bcomb)
{
    int k = blockIdx.x;
    int n = blockIdx.y*256 + threadIdx.x;
    float s = 0.f;
    for (int p=0;p<256;++p)
        s += zw_b[k*256+p] * alpha[(size_t)k*262144 + (size_t)p*1024 + n];
    bcomb[(size_t)k*1024 + n] = s;
}

// =====================================================================
// pointwise cell device functions
// =====================================================================
__device__ __forceinline__ void breduce2(float& a, float& b, volatile float* buf, int tid){
    #pragma unroll
    for (int off = 32; off > 0; off >>= 1) { a += __shfl_xor(a, off); b += __shfl_xor(b, off); }
    __syncthreads();
    if ((tid & 63) == 0) { buf[(tid>>6)*2] = a; buf[(tid>>6)*2+1] = b; }
    __syncthreads();
    a = buf[0] + buf[2] + buf[4] + buf[6];
    b = buf[1] + buf[3] + buf[5] + buf[7];
}

struct Params {
    const float *x;
    const float *bias4, *lna_g, *lna_b, *ln_g, *ln_b;
    const float *hlna_g, *hlna_b, *hln_g, *hln_b;
    const float *fcW, *fcb;
    const unsigned short *wcat1bf, *wxbf, *whbf, *wcombbf;
    const float *bcomb, *bias1;
    float *act1, *c, *ch, *gpart, *scb, *xghg;
    float *out;
};

__device__ void hyper_cell_dev(int b, const Params& p)
{
    __shared__ float buf[8];
    int tid = threadIdx.x;
    float v[4];
    #pragma unroll
    for (int g=0; g<4; ++g){
        int idx = b*1024 + g*256 + tid;
        v[g] = p.gpart[idx] + p.gpart[131072 + idx] + p.gpart[262144 + idx] + p.gpart[393216 + idx]
             + p.bias1[g*256 + tid];
    }
    #pragma unroll
    for (int g=0; g<4; ++g){
        float s = v[g], ss = v[g]*v[g];
        breduce2(s, ss, buf, tid);
        float m = s * (1.f/256.f);
        float var = ss * (1.f/256.f) - m*m;
        v[g] = (v[g]-m)*rsqrtf(var + EPS)*p.hlna_g[g*256+tid] + p.hlna_b[g*256+tid];
    }
    float chp = p.ch[b*256 + tid];
    float cn = sigm(v[1])*chp + sigm(v[0])*tanhf(v[2]);
    float s = cn, ss = cn*cn;
    breduce2(s, ss, buf, tid);
    float m = s*(1.f/256.f);
    float var = ss*(1.f/256.f) - m*m;
    float hn = sigm(v[3]) * tanhf((cn-m)*rsqrtf(var + EPS)*p.hln_g[tid] + p.hln_b[tid]);
    p.ch[b*256 + tid] = cn;
    p.act1[b*1280 + 1024 + tid] = hn;
}

__device__ void main_cell_dev(int b, const Params& p)
{
    __shared__ float buf[8];
    int tid = threadIdx.x;
    float gn[4][4];
    #pragma unroll
    for (int k=0;k<4;++k){
        float pre[4]; float s=0.f, ss=0.f;
        #pragma unroll
        for (int j=0;j<4;++j){
            int h = j*256 + tid;
            int n = k*1024 + h;
            int bh = b*1024 + h;
            float xgv = p.xghg[b*4096 + n];
            float hgv = p.xghg[524288 + b*4096 + n];
            float pr = p.scb[k*131072 + bh]*xgv + p.scb[(4+k)*131072 + bh]*hgv
                     + p.bias4[n] + p.scb[(8+k)*131072 + bh];
            pre[j] = pr; s += pr; ss += pr*pr;
        }
        breduce2(s, ss, buf, tid);
        float m = s*(1.f/1024.f);
        float var = ss*(1.f/1024.f) - m*m;
        float rs = rsqrtf(var + EPS);
        #pragma unroll
        for (int j=0;j<4;++j){
            int h=j*256+tid, n=k*1024+h;
            gn[k][j] = (pre[j]-m)*rs*p.lna_g[n] + p.lna_b[n];
        }
    }
    float cnv[4]; float s=0.f, ss=0.f;
    #pragma unroll
    for (int j=0;j<4;++j){
        int h=j*256+tid;
        float cv = p.c[b*1024+h];
        float xv = sigm(gn[2][j])*cv + sigm(gn[0][j])*tanhf(gn[1][j]);
        cnv[j]=xv; s+=xv; ss+=xv*xv;
    }
    breduce2(s, ss, buf, tid);
    float m=s*(1.f/1024.f);
    float var=ss*(1.f/1024.f)-m*m;
    float rs=rsqrtf(var + EPS);
    #pragma unroll
    for (int j=0;j<4;++j){
        int h=j*256+tid;
        float hv = sigm(gn[3][j])*tanhf((cnv[j]-m)*rs*p.ln_g[h] + p.ln_b[h]);
        p.c[b*1024+h] = cnv[j];
        p.act1[b*1280 + h] = hv;
    }
}

// =====================================================================
// THE persistent cooperative kernel: all 512 steps, 4 grid syncs/step
// =====================================================================
__global__ __launch_bounds__(256, 2) void k_persist(Params p)
{
    cg::grid_group grid = cg::this_grid();
    const int nb = gridDim.x, bid = blockIdx.x;

    for (int t = 0; t < T_STEPS; ++t) {
        const float* xt = p.x + (size_t)t*BATCH*DIN;

        // ---- phase A: hyper gates (splitK4) + xg + hg   [384 jobs] ----
        for (int job = bid; job < 384; job += nb) {
            if (job < 128) {
                int sp = job >> 5, r = job & 31;
                gemm_mfma(xt, 256, 256, p.act1, 1280, p.wcat1bf, 1536, nullptr,
                          p.gpart + (size_t)sp*131072, 1024, 384, sp*384, r >> 3, r & 7);
            } else if (job < 256) {
                int r = job - 128;
                gemm_mfma(xt, 256, KSPLIT_NONE, xt, 256, p.wxbf, 256, nullptr,
                          p.xghg, 4096, 256, 0, r >> 5, r & 31);
            } else {
                int r = job - 256;
                gemm_mfma(p.act1, 1280, KSPLIT_NONE, p.act1, 1280, p.whbf, 1024, nullptr,
                          p.xghg + 524288, 4096, 1024, 0, r >> 5, r & 31);
            }
        }
        grid.sync();

        // ---- phase B: hyper cell  [128 jobs] ----
        for (int b = bid; b < 128; b += nb) hyper_cell_dev(b, p);
        grid.sync();

        // ---- phase C: 12 sc GEMMs  [384 jobs] ----
        for (int job = bid; job < 384; job += nb) {
            int kk = job >> 5, r = job & 31;
            const float* bias = (kk < 8) ? (p.bcomb + (size_t)kk*1024) : nullptr;
            gemm_mfma(p.act1 + 1024, 1280, KSPLIT_NONE, p.act1 + 1024, 1280,
                      p.wcombbf + (size_t)kk*262144, 256, bias,
                      p.scb + (size_t)kk*131072, 1024, 256, 0, r >> 3, r & 7);
        }
        grid.sync();

        // ---- phase D: main cell  [128 jobs] ----
        for (int b = bid; b < 128; b += nb) main_cell_dev(b, p);
        grid.sync();
    }

    // ---- final FC ----
    for (int b = bid; b < 128; b += nb) {
        int o = threadIdx.x;
        if (o < OUTN) {
            const float* h = p.act1 + (size_t)b*1280;
            float s = p.fcb[o];
            for (int k=0;k<1024;++k) s += h[k]*p.fcW[(size_t)o*1024 + k];
            p.out[b*OUTN + o] = s;
        }
    }
}

// =====================================================================
// launch
// =====================================================================
extern "C" void kernel_launch(void* const* d_in, const int* in_sizes, int n_in,
                              void* d_out, int out_size, void* d_ws, size_t ws_size,
                              hipStream_t stream)
{
    const float* x        = (const float*)d_in[0];
    const float* Wx       = (const float*)d_in[1];
    const float* Wh       = (const float*)d_in[2];
    const float* bias     = (const float*)d_in[3];
    const float* lna_g    = (const float*)d_in[4];
    const float* lna_b    = (const float*)d_in[5];
    const float* ln_g     = (const float*)d_in[6];
    const float* ln_b     = (const float*)d_in[7];
    const float* zb       = (const float*)d_in[8];
    const float* zbeta    = (const float*)d_in[9];
    const float* zw_w     = (const float*)d_in[10];
    const float* zw_b     = (const float*)d_in[11];
    const float* alpha    = (const float*)d_in[12];
    const float* hyp_Wx   = (const float*)d_in[13];
    const float* hyp_bx   = (const float*)d_in[14];
    const float* hyp_Wh   = (const float*)d_in[15];
    const float* hyp_bh   = (const float*)d_in[16];
    const float* hlna_g   = (const float*)d_in[17];
    const float* hlna_b   = (const float*)d_in[18];
    const float* hln_g    = (const float*)d_in[19];
    const float* hln_b    = (const float*)d_in[20];
    const float* fcW      = (const float*)d_in[21];
    const float* fcb      = (const float*)d_in[22];

    // ---- workspace carve-up (identical to round 2) ----
    unsigned short* wcat1bf = (unsigned short*)d_ws;          // 1024*1536
    unsigned short* wxbf    = wcat1bf + 1572864;              // 4096*256
    unsigned short* whbf    = wxbf + 1048576;                 // 4096*1024
    unsigned short* wcombbf = whbf + 4194304;                 // 12*1024*256
    float* bcomb = (float*)(wcombbf + 3145728);               // 8*1024
    float* bias1 = bcomb + 8192;                              // 1024
    float* act1  = bias1 + 1024;                              // 128*1280
    float* c     = act1 + 163840;                             // 128*1024
    float* ch    = c + 131072;                                // 128*256
    float* stepbuf = ch + 32768;
    float* gpart = stepbuf;                                   // 4*128*1024
    float* scb   = gpart + 524288;                            // 12*128*1024
    float* xghg  = scb + 1572864;                             // 2*128*4096
    float* wcombf32 = stepbuf;                                // prep-time alias

    // ---- prep ----
    k_prep_convert<<<(7144448 + 255)/256, 256, 0, stream>>>(
        hyp_Wx, hyp_Wh, hyp_bx, hyp_bh, Wx, Wh,
        wcat1bf, wxbf, whbf, bias1, act1, c, ch);
    k_prep_wcomb<<<dim3(8,16,12), 128, 0, stream>>>(zw_w, zb, alpha, zbeta, wcombf32);
    k_prep_bcomb<<<dim3(8,4), 256, 0, stream>>>(zw_b, alpha, bcomb);
    k_prep_cvtcomb<<<(3145728 + 255)/256, 256, 0, stream>>>(wcombf32, wcombbf);

    // ---- persistent cooperative kernel: entire 512-step scan + FC ----
    Params p;
    p.x = x; p.bias4 = bias;
    p.lna_g = lna_g; p.lna_b = lna_b; p.ln_g = ln_g; p.ln_b = ln_b;
    p.hlna_g = hlna_g; p.hlna_b = hlna_b; p.hln_g = hln_g; p.hln_b = hln_b;
    p.fcW = fcW; p.fcb = fcb;
    p.wcat1bf = wcat1bf; p.wxbf = wxbf; p.whbf = whbf; p.wcombbf = wcombbf;
    p.bcomb = bcomb; p.bias1 = bias1;
    p.act1 = act1; p.c = c; p.ch = ch;
    p.gpart = gpart; p.scb = scb; p.xghg = xghg;
    p.out = (float*)d_out;

    int maxb = 0;
    hipOccupancyMaxActiveBlocksPerMultiprocessor(&maxb, (const void*)k_persist, 256, 0);
    if (maxb < 1) maxb = 1;
    int grid = maxb * 256;          // 256 CUs on MI355X
    if (grid > 512) grid = 512;

    void* args[] = { (void*)&p };
    hipLaunchCooperativeKernel((const void*)k_persist, dim3(grid), dim3(256),
                               args, 0, stream);
}

// Round 5
// 52741.742 us; speedup vs baseline: 1.6459x; 1.6459x over previous
//
#include <hip/hip_runtime.h>
#include <math.h>

// ---------------- problem dims ----------------
#define T_STEPS 512
#define BATCH   128
#define DIN     256
#define HMAIN   1024
#define HHYP    256
#define OUTN    128
#define EPS     1e-3f

#define KSPLIT_NONE (1<<30)

typedef __attribute__((ext_vector_type(4))) float f32x4;
typedef __attribute__((ext_vector_type(8))) short s16x8;

// agent-scope (device) coherent accesses: bypass the non-coherent per-XCD L2s.
#define AG_LD(p)   __hip_atomic_load((p), __ATOMIC_RELAXED, __HIP_MEMORY_SCOPE_AGENT)
#define AG_ST(p,v) __hip_atomic_store((p), (v), __ATOMIC_RELAXED, __HIP_MEMORY_SCOPE_AGENT)

__device__ __forceinline__ float sigm(float x){ return 1.f/(1.f + expf(-x)); }

__device__ __forceinline__ unsigned short f2bf(float f){
    union { float f; unsigned u; } x; x.f = f;
    unsigned r = x.u + 0x7FFFu + ((x.u >> 16) & 1u);   // RNE
    return (unsigned short)(r >> 16);
}

// =====================================================================
// fp32 tiled GEMM (prep only): tile 32x64, KT=32, 128 thr, 4x4 micro
// =====================================================================
#define BM 32
#define BN 64
#define KT 32
__device__ void gemm_dev(const float* __restrict__ A1, int lda1, int ksplit,
                         const float* __restrict__ A2, int lda2,
                         const float* __restrict__ Bp, int ldb, int b_nk,
                         const float* __restrict__ bias,
                         float* __restrict__ C, int ldc,
                         int K, int k0, int mtile, int ntile)
{
    __shared__ __align__(16) float As[KT][BM+4];
    __shared__ __align__(16) float Bs[KT][BN+4];
    const int tid = threadIdx.x;
    const int mt = tid >> 4, nt = tid & 15;
    const int m0g = mtile*BM, n0g = ntile*BN;
    float acc[4][4];
    #pragma unroll
    for (int i=0;i<4;++i) { acc[i][0]=0;acc[i][1]=0;acc[i][2]=0;acc[i][3]=0; }
    for (int kt = 0; kt < K; kt += KT) {
        __syncthreads();
        #pragma unroll
        for (int i=0;i<8;++i){
            int e = tid + i*128;
            int m = e >> 5, k = e & 31;
            int gk = k0 + kt + k, gm = m0g + m;
            float v = (gk < ksplit) ? A1[(size_t)gm*lda1 + gk]
                                    : A2[(size_t)gm*lda2 + (gk - ksplit)];
            As[k][m] = v;
        }
        if (b_nk) {
            #pragma unroll
            for (int i=0;i<16;++i){
                int e = tid + i*128;
                int n = e >> 5, k = e & 31;
                Bs[k][n] = Bp[(size_t)(n0g + n)*ldb + (k0 + kt + k)];
            }
        } else {
            #pragma unroll
            for (int i=0;i<16;++i){
                int e = tid + i*128;
                int k = e >> 6, n = e & 63;
                Bs[k][n] = Bp[(size_t)(k0 + kt + k)*ldb + (n0g + n)];
            }
        }
        __syncthreads();
        #pragma unroll
        for (int k=0;k<KT;++k){
            float4 av = *(const float4*)(&As[k][4*mt]);
            float4 bv = *(const float4*)(&Bs[k][4*nt]);
            acc[0][0]+=av.x*bv.x; acc[0][1]+=av.x*bv.y; acc[0][2]+=av.x*bv.z; acc[0][3]+=av.x*bv.w;
            acc[1][0]+=av.y*bv.x; acc[1][1]+=av.y*bv.y; acc[1][2]+=av.y*bv.z; acc[1][3]+=av.y*bv.w;
            acc[2][0]+=av.z*bv.x; acc[2][1]+=av.z*bv.y; acc[2][2]+=av.z*bv.z; acc[2][3]+=av.z*bv.w;
            acc[3][0]+=av.w*bv.x; acc[3][1]+=av.w*bv.y; acc[3][2]+=av.w*bv.z; acc[3][3]+=av.w*bv.w;
        }
    }
    #pragma unroll
    for (int i=0;i<4;++i){
        int gm = m0g + 4*mt + i;
        #pragma unroll
        for (int j=0;j<4;++j){
            int gn = n0g + 4*nt + j;
            float v = acc[i][j];
            if (bias) v += bias[gn];
            C[(size_t)gm*ldc + gn] = v;
        }
    }
}

// =====================================================================
// bf16 MFMA GEMM, M=16 x N=128 tile, KT=32, 256 thr (4 waves).
// =====================================================================
#define ASTR 40
__device__ void gemm16(const float* __restrict__ A1, int lda1, int ksplit,
                       const float* __restrict__ A2, int lda2,
                       const unsigned short* __restrict__ B, int ldb,
                       const float* __restrict__ bias,
                       float* __restrict__ C, int ldc,
                       int K, int k0, int m0g, int n0g)
{
    __shared__ __align__(16) unsigned short As[16*ASTR];
    __shared__ __align__(16) unsigned short Bs[128*ASTR];
    const int tid = threadIdx.x;
    const int lane = tid & 63, w = tid >> 6;
    const int wn = w * 32;
    const int fr = lane & 15, koff = (lane >> 4) * 8;

    f32x4 acc0 = {0.f,0.f,0.f,0.f}, acc1 = {0.f,0.f,0.f,0.f};

    const int arow = tid >> 4, akc = (tid & 15) * 2;   // A: 16x32, 2 elems/thr
    for (int kt = 0; kt < K; kt += 32) {
        __syncthreads();
        {   // A tile (fp32 -> bf16), agent loads (IF$-coherent)
            int gk = k0 + kt + akc;
            int gm = m0g + arow;
            const float* src = (gk < ksplit) ? (A1 + (size_t)gm*lda1 + gk)
                                             : (A2 + (size_t)gm*lda2 + (gk - ksplit));
            float v0 = AG_LD(src);
            float v1 = AG_LD(src + 1);
            As[arow*ASTR + akc]     = f2bf(v0);
            As[arow*ASTR + akc + 1] = f2bf(v1);
        }
        #pragma unroll
        for (int i=0;i<4;++i){   // B tile: 128 x 32 bf16, cached loads
            int e = tid + i*256;
            int n = e >> 3, kc = (e & 7) * 4;
            ushort4 bv = *(const ushort4*)(B + (size_t)(n0g + n)*ldb + (k0 + kt + kc));
            unsigned short* d = &Bs[n*ASTR + kc];
            d[0] = bv.x; d[1] = bv.y; d[2] = bv.z; d[3] = bv.w;
        }
        __syncthreads();
        s16x8 af  = *(const s16x8*)&As[fr*ASTR + koff];
        s16x8 bf0 = *(const s16x8*)&Bs[(wn      + fr)*ASTR + koff];
        s16x8 bf1 = *(const s16x8*)&Bs[(wn + 16 + fr)*ASTR + koff];
        acc0 = __builtin_amdgcn_mfma_f32_16x16x32_bf16(af, bf0, acc0, 0, 0, 0);
        acc1 = __builtin_amdgcn_mfma_f32_16x16x32_bf16(af, bf1, acc1, 0, 0, 0);
    }
    #pragma unroll
    for (int j=0;j<2;++j){
        f32x4 a = j ? acc1 : acc0;
        int gn = n0g + wn + j*16 + fr;
        float bb = bias ? bias[gn] : 0.f;
        #pragma unroll
        for (int r=0;r<4;++r){
            int gm = m0g + (lane >> 4)*4 + r;
            AG_ST(&C[(size_t)gm*ldc + gn], a[r] + bb);
        }
    }
}

// =====================================================================
// prep kernels
// =====================================================================
__global__ __launch_bounds__(256) void k_prep_convert(
    const float* __restrict__ hyp_Wx, const float* __restrict__ hyp_Wh,
    const float* __restrict__ hyp_bx, const float* __restrict__ hyp_bh,
    const float* __restrict__ Wx, const float* __restrict__ Wh,
    unsigned short* __restrict__ wcat1bf, unsigned short* __restrict__ wxbf,
    unsigned short* __restrict__ whbf, float* __restrict__ bias1,
    float* __restrict__ act1, float* __restrict__ c, float* __restrict__ ch,
    int* __restrict__ barrier_mem)
{
    size_t i = (size_t)blockIdx.x*256 + threadIdx.x;
    if (i < 1572864u) {
        int n = (int)(i / 1536), k = (int)(i % 1536);
        float v = (k < 1280) ? hyp_Wx[(size_t)n*1280 + k] : hyp_Wh[(size_t)n*256 + (k-1280)];
        wcat1bf[i] = f2bf(v); return;
    }
    i -= 1572864u;
    if (i < 1048576u) { wxbf[i] = f2bf(Wx[i]); return; }
    i -= 1048576u;
    if (i < 4194304u) { whbf[i] = f2bf(Wh[i]); return; }
    i -= 4194304u;
    if (i < 1024u) { bias1[i] = hyp_bx[i] + hyp_bh[i]; return; }
    i -= 1024u;
    if (i < 163840u) { act1[i] = 0.f; return; }
    i -= 163840u;
    if (i < 131072u) { c[i] = 0.f; return; }
    i -= 131072u;
    if (i < 32768u) { ch[i] = 0.f; return; }
    i -= 32768u;
    if (i < 768u) { barrier_mem[i] = 0; return; }
}

__global__ __launch_bounds__(128) void k_prep_wcomb(
    const float* __restrict__ zw_w, const float* __restrict__ zb,
    const float* __restrict__ alpha, const float* __restrict__ zbeta,
    float* __restrict__ wcombf32)
{
    int kk = blockIdx.z;
    const float* A = (kk < 8) ? (zw_w + (size_t)kk*65536) : (zb + (size_t)(kk-8)*65536);
    const float* Bm = (kk < 8) ? (alpha + (size_t)kk*262144) : (zbeta + (size_t)(kk-8)*262144);
    gemm_dev(A, 256, KSPLIT_NONE, A, 256, Bm, 1024, 0, nullptr,
             wcombf32 + (size_t)kk*262144, 1024, 256, 0, blockIdx.x, blockIdx.y);
}

__global__ __launch_bounds__(256) void k_prep_cvtcomb(
    const float* __restrict__ wcombf32, unsigned short* __restrict__ wcombbf)
{
    size_t i = (size_t)blockIdx.x*256 + threadIdx.x;
    if (i >= 3145728u) return;
    int kk = (int)(i / 262144u);
    int r  = (int)(i % 262144u);
    int n = r / 256, k = r % 256;
    wcombbf[i] = f2bf(wcombf32[(size_t)kk*262144 + (size_t)k*1024 + n]);
}

__global__ __launch_bounds__(256) void k_prep_bcomb(
    const float* __restrict__ zw_b, const float* __restrict__ alpha,
    float* __restrict__ bcomb)
{
    int k = blockIdx.x;
    int n = blockIdx.y*256 + threadIdx.x;
    float s = 0.f;
    for (int p=0;p<256;++p)
        s += zw_b[k*256+p] * alpha[(size_t)k*262144 + (size_t)p*1024 + n];
    bcomb[(size_t)k*1024 + n] = s;
}

// =====================================================================
// params
// =====================================================================
struct Params {
    const float *x;
    const float *bias4, *lna_g, *lna_b, *ln_g, *ln_b;
    const float *hlna_g, *hlna_b, *hln_g, *hln_b;
    const float *fcW, *fcb;
    const unsigned short *wcat1bf, *wxbf, *whbf, *wcombbf;
    const float *bcomb, *bias1;
    float *act1, *c, *ch, *gpart, *scb, *xghg;
    int *arrive, *release;
    float *out;
};

// =====================================================================
// group barrier: 64 blocks, distributed arrival stores + leader scan.
// agent-scope relaxed atomics only — no L2 flushes. Deadlock-free under
// partial residency because groups are contiguous in block index and
// only depend on lower-indexed groups retiring.
// =====================================================================
__device__ __forceinline__ void gbar(const Params& p, int g, int lb, int gen)
{
    __syncthreads();   // per-wave vmcnt(0) drain before s_barrier
    if (threadIdx.x == 0) {
        asm volatile("s_waitcnt vmcnt(0)" ::: "memory");
        AG_ST(&p.arrive[g*64 + lb], gen);
    }
    if (lb == 0) {
        if (threadIdx.x < 64) {
            while (AG_LD(&p.arrive[g*64 + threadIdx.x]) < gen)
                __builtin_amdgcn_s_sleep(2);
        }
        __syncthreads();
        if (threadIdx.x == 0) AG_ST(&p.release[g*32], gen);
    } else {
        if (threadIdx.x == 0) {
            while (AG_LD(&p.release[g*32]) < gen)
                __builtin_amdgcn_s_sleep(2);
        }
    }
    __syncthreads();
}

// =====================================================================
// pointwise cell device functions (agent loads/stores on intermediates)
// =====================================================================
__device__ __forceinline__ void breduce2(float& a, float& b, volatile float* buf, int tid){
    #pragma unroll
    for (int off = 32; off > 0; off >>= 1) { a += __shfl_xor(a, off); b += __shfl_xor(b, off); }
    __syncthreads();
    if ((tid & 63) == 0) { buf[(tid>>6)*2] = a; buf[(tid>>6)*2+1] = b; }
    __syncthreads();
    a = buf[0] + buf[2] + buf[4] + buf[6];
    b = buf[1] + buf[3] + buf[5] + buf[7];
}

__device__ void hyper_cell_dev(int b, const Params& p)
{
    __shared__ float buf[8];
    int tid = threadIdx.x;
    float v[4];
    #pragma unroll
    for (int g=0; g<4; ++g){
        int idx = b*1024 + g*256 + tid;
        v[g] = AG_LD(&p.gpart[idx]) + AG_LD(&p.gpart[131072 + idx]);  // bias1 folded into part0
    }
    #pragma unroll
    for (int g=0; g<4; ++g){
        float s = v[g], ss = v[g]*v[g];
        breduce2(s, ss, buf, tid);
        float m = s * (1.f/256.f);
        float var = ss * (1.f/256.f) - m*m;
        v[g] = (v[g]-m)*rsqrtf(var + EPS)*p.hlna_g[g*256+tid] + p.hlna_b[g*256+tid];
    }
    float chp = AG_LD(&p.ch[b*256 + tid]);
    float cn = sigm(v[1])*chp + sigm(v[0])*tanhf(v[2]);
    float s = cn, ss = cn*cn;
    breduce2(s, ss, buf, tid);
    float m = s*(1.f/256.f);
    float var = ss*(1.f/256.f) - m*m;
    float hn = sigm(v[3]) * tanhf((cn-m)*rsqrtf(var + EPS)*p.hln_g[tid] + p.hln_b[tid]);
    AG_ST(&p.ch[b*256 + tid], cn);
    AG_ST(&p.act1[b*1280 + 1024 + tid], hn);
}

__device__ void main_cell_dev(int b, const Params& p)
{
    __shared__ float buf[8];
    int tid = threadIdx.x;
    float gn[4][4];
    #pragma unroll
    for (int k=0;k<4;++k){
        float pre[4]; float s=0.f, ss=0.f;
        #pragma unroll
        for (int j=0;j<4;++j){
            int h = j*256 + tid;
            int n = k*1024 + h;
            int bh = b*1024 + h;
            float xgv = AG_LD(&p.xghg[b*4096 + n]);
            float hgv = AG_LD(&p.xghg[524288 + b*4096 + n]);
            float pr = AG_LD(&p.scb[k*131072 + bh])*xgv + AG_LD(&p.scb[(4+k)*131072 + bh])*hgv
                     + p.bias4[n] + AG_LD(&p.scb[(8+k)*131072 + bh]);
            pre[j] = pr; s += pr; ss += pr*pr;
        }
        breduce2(s, ss, buf, tid);
        float m = s*(1.f/1024.f);
        float var = ss*(1.f/1024.f) - m*m;
        float rs = rsqrtf(var + EPS);
        #pragma unroll
        for (int j=0;j<4;++j){
            int h=j*256+tid, n=k*1024+h;
            gn[k][j] = (pre[j]-m)*rs*p.lna_g[n] + p.lna_b[n];
        }
    }
    float cnv[4]; float s=0.f, ss=0.f;
    #pragma unroll
    for (int j=0;j<4;++j){
        int h=j*256+tid;
        float cv = AG_LD(&p.c[b*1024+h]);
        float xv = sigm(gn[2][j])*cv + sigm(gn[0][j])*tanhf(gn[1][j]);
        cnv[j]=xv; s+=xv; ss+=xv*xv;
    }
    breduce2(s, ss, buf, tid);
    float m=s*(1.f/1024.f);
    float var=ss*(1.f/1024.f)-m*m;
    float rs=rsqrtf(var + EPS);
    #pragma unroll
    for (int j=0;j<4;++j){
        int h=j*256+tid;
        float hv = sigm(gn[3][j])*tanhf((cnv[j]-m)*rs*p.ln_g[h] + p.ln_b[h]);
        AG_ST(&p.c[b*1024+h], cnv[j]);
        AG_ST(&p.act1[b*1280 + h], hv);
    }
}

__device__ void fc_dev(int b, const Params& p)
{
    __shared__ float hs[1024];
    int tid = threadIdx.x;
    for (int i=tid; i<1024; i+=256) hs[i] = AG_LD(&p.act1[(size_t)b*1280 + i]);
    __syncthreads();
    if (tid < OUTN) {
        float s = p.fcb[tid];
        const float* wrow = p.fcW + (size_t)tid*1024;
        for (int k=0;k<1024;++k) s += hs[k]*wrow[k];
        p.out[b*OUTN + tid] = s;
    }
}

// =====================================================================
// persistent kernel: 8 groups x 64 blocks; group g owns rows 16g..16g+15
// 4 group-local barriers per step. Plain launch — no cooperative API.
// =====================================================================
__global__ __launch_bounds__(256, 2) void k_persist(Params p)
{
    const int bid = blockIdx.x;
    const int g  = bid >> 6;       // group 0..7
    const int lb = bid & 63;       // local block 0..63
    const int m0 = g * 16;         // first batch row of this group
    int gen = 1;

    for (int t = 0; t < T_STEPS; ++t) {
        const float* xt = p.x + (size_t)t*BATCH*DIN;

        // ---- phase A: hyper gates (splitK2, bias in part0) + hg + xg [80 jobs] ----
        for (int job = lb; job < 80; job += 64) {
            if (job < 16) {
                int sp = job & 1, nt = job >> 1;
                gemm16(xt, 256, 256, p.act1, 1280, p.wcat1bf, 1536,
                       sp ? nullptr : p.bias1,
                       p.gpart + (size_t)sp*131072, 1024,
                       768, sp*768, m0, nt*128);
            } else if (job < 48) {
                int nt = job - 16;
                gemm16(p.act1, 1280, KSPLIT_NONE, p.act1, 1280, p.whbf, 1024, nullptr,
                       p.xghg + 524288, 4096, 1024, 0, m0, nt*128);
            } else {
                int nt = job - 48;
                gemm16(xt, 256, KSPLIT_NONE, xt, 256, p.wxbf, 256, nullptr,
                       p.xghg, 4096, 256, 0, m0, nt*128);
            }
        }
        gbar(p, g, lb, gen++);

        // ---- phase B: hyper cell (16 rows) ----
        if (lb < 16) hyper_cell_dev(m0 + lb, p);
        gbar(p, g, lb, gen++);

        // ---- phase C: 12 sc GEMMs [96 jobs] ----
        for (int job = lb; job < 96; job += 64) {
            int kk = job >> 3, nt = job & 7;
            gemm16(p.act1 + 1024, 1280, KSPLIT_NONE, p.act1 + 1024, 1280,
                   p.wcombbf + (size_t)kk*262144, 256,
                   kk < 8 ? p.bcomb + (size_t)kk*1024 : nullptr,
                   p.scb + (size_t)kk*131072, 1024,
                   256, 0, m0, nt*128);
        }
        gbar(p, g, lb, gen++);

        // ---- phase D: main cell (16 rows) ----
        if (lb < 16) main_cell_dev(m0 + lb, p);
        gbar(p, g, lb, gen++);
    }

    // ---- final FC: group-local, no further sync needed ----
    if (lb < 16) fc_dev(m0 + lb, p);
}

// =====================================================================
// launch
// =====================================================================
extern "C" void kernel_launch(void* const* d_in, const int* in_sizes, int n_in,
                              void* d_out, int out_size, void* d_ws, size_t ws_size,
                              hipStream_t stream)
{
    const float* x        = (const float*)d_in[0];
    const float* Wx       = (const float*)d_in[1];
    const float* Wh       = (const float*)d_in[2];
    const float* bias     = (const float*)d_in[3];
    const float* lna_g    = (const float*)d_in[4];
    const float* lna_b    = (const float*)d_in[5];
    const float* ln_g     = (const float*)d_in[6];
    const float* ln_b     = (const float*)d_in[7];
    const float* zb       = (const float*)d_in[8];
    const float* zbeta    = (const float*)d_in[9];
    const float* zw_w     = (const float*)d_in[10];
    const float* zw_b     = (const float*)d_in[11];
    const float* alpha    = (const float*)d_in[12];
    const float* hyp_Wx   = (const float*)d_in[13];
    const float* hyp_bx   = (const float*)d_in[14];
    const float* hyp_Wh   = (const float*)d_in[15];
    const float* hyp_bh   = (const float*)d_in[16];
    const float* hlna_g   = (const float*)d_in[17];
    const float* hlna_b   = (const float*)d_in[18];
    const float* hln_g    = (const float*)d_in[19];
    const float* hln_b    = (const float*)d_in[20];
    const float* fcW      = (const float*)d_in[21];
    const float* fcb      = (const float*)d_in[22];

    // ---- workspace carve-up ----
    unsigned short* wcat1bf = (unsigned short*)d_ws;          // 1024*1536
    unsigned short* wxbf    = wcat1bf + 1572864;              // 4096*256
    unsigned short* whbf    = wxbf + 1048576;                 // 4096*1024
    unsigned short* wcombbf = whbf + 4194304;                 // 12*1024*256
    float* bcomb = (float*)(wcombbf + 3145728);               // 8*1024
    float* bias1 = bcomb + 8192;                              // 1024
    float* act1  = bias1 + 1024;                              // 128*1280
    float* c     = act1 + 163840;                             // 128*1024
    float* ch    = c + 131072;                                // 128*256
    float* stepbuf = ch + 32768;                              // 3,145,728 floats
    float* gpart = stepbuf;                                   // 4*128*1024 (2 used)
    float* scb   = gpart + 524288;                            // 12*128*1024
    float* xghg  = scb + 1572864;                             // 2*128*4096
    float* wcombf32 = stepbuf;                                // prep-time alias
    int* barrier_mem = (int*)(stepbuf + 3145728);             // 768 ints

    // ---- prep ----
    k_prep_convert<<<(7145216 + 255)/256, 256, 0, stream>>>(
        hyp_Wx, hyp_Wh, hyp_bx, hyp_bh, Wx, Wh,
        wcat1bf, wxbf, whbf, bias1, act1, c, ch, barrier_mem);
    k_prep_wcomb<<<dim3(8,16,12), 128, 0, stream>>>(zw_w, zb, alpha, zbeta, wcombf32);
    k_prep_bcomb<<<dim3(8,4), 256, 0, stream>>>(zw_b, alpha, bcomb);
    k_prep_cvtcomb<<<(3145728 + 255)/256, 256, 0, stream>>>(wcombf32, wcombbf);

    // ---- persistent kernel: entire 512-step scan + FC, plain launch ----
    Params p;
    p.x = x; p.bias4 = bias;
    p.lna_g = lna_g; p.lna_b = lna_b; p.ln_g = ln_g; p.ln_b = ln_b;
    p.hlna_g = hlna_g; p.hlna_b = hlna_b; p.hln_g = hln_g; p.hln_b = hln_b;
    p.fcW = fcW; p.fcb = fcb;
    p.wcat1bf = wcat1bf; p.wxbf = wxbf; p.whbf = whbf; p.wcombbf = wcombbf;
    p.bcomb = bcomb; p.bias1 = bias1;
    p.act1 = act1; p.c = c; p.ch = ch;
    p.gpart = gpart; p.scb = scb; p.xghg = xghg;
    p.arrive = barrier_mem; p.release = barrier_mem + 512;
    p.out = (float*)d_out;

    k_persist<<<512, 256, 0, stream>>>(p);
}

// Round 7
// 46979.996 us; speedup vs baseline: 1.8478x; 1.1226x over previous
//
#include <hip/hip_runtime.h>
#include <math.h>

// ---------------- problem dims ----------------
#define T_STEPS 512
#define BATCH   128
#define DIN     256
#define HMAIN   1024
#define HHYP    256
#define OUTN    128
#define EPS     1e-3f

#define KSPLIT_NONE (1<<30)

typedef __attribute__((ext_vector_type(4))) float f32x4;
typedef __attribute__((ext_vector_type(8))) short s16x8;
typedef __attribute__((ext_vector_type(8))) unsigned short u16x8;

// agent-scope (device) coherent accesses: bypass the non-coherent per-XCD L2s.
#define AG_LD(p)   __hip_atomic_load((p), __ATOMIC_RELAXED, __HIP_MEMORY_SCOPE_AGENT)
#define AG_ST(p,v) __hip_atomic_store((p), (v), __ATOMIC_RELAXED, __HIP_MEMORY_SCOPE_AGENT)

__device__ __forceinline__ float sigm(float x){ return 1.f/(1.f + expf(-x)); }

__device__ __forceinline__ unsigned short f2bf(float f){
    union { float f; unsigned u; } x; x.f = f;
    unsigned r = x.u + 0x7FFFu + ((x.u >> 16) & 1u);   // RNE
    return (unsigned short)(r >> 16);
}

// =====================================================================
// fp32 tiled GEMM (prep only): tile 32x64, KT=32, 128 thr, 4x4 micro
// =====================================================================
#define BM 32
#define BN 64
#define KT 32
__device__ void gemm_dev(const float* __restrict__ A1, int lda1, int ksplit,
                         const float* __restrict__ A2, int lda2,
                         const float* __restrict__ Bp, int ldb, int b_nk,
                         const float* __restrict__ bias,
                         float* __restrict__ C, int ldc,
                         int K, int k0, int mtile, int ntile)
{
    __shared__ __align__(16) float As[KT][BM+4];
    __shared__ __align__(16) float Bs[KT][BN+4];
    const int tid = threadIdx.x;
    const int mt = tid >> 4, nt = tid & 15;
    const int m0g = mtile*BM, n0g = ntile*BN;
    float acc[4][4];
    #pragma unroll
    for (int i=0;i<4;++i) { acc[i][0]=0;acc[i][1]=0;acc[i][2]=0;acc[i][3]=0; }
    for (int kt = 0; kt < K; kt += KT) {
        __syncthreads();
        #pragma unroll
        for (int i=0;i<8;++i){
            int e = tid + i*128;
            int m = e >> 5, k = e & 31;
            int gk = k0 + kt + k, gm = m0g + m;
            float v = (gk < ksplit) ? A1[(size_t)gm*lda1 + gk]
                                    : A2[(size_t)gm*lda2 + (gk - ksplit)];
            As[k][m] = v;
        }
        if (b_nk) {
            #pragma unroll
            for (int i=0;i<16;++i){
                int e = tid + i*128;
                int n = e >> 5, k = e & 31;
                Bs[k][n] = Bp[(size_t)(n0g + n)*ldb + (k0 + kt + k)];
            }
        } else {
            #pragma unroll
            for (int i=0;i<16;++i){
                int e = tid + i*128;
                int k = e >> 6, n = e & 63;
                Bs[k][n] = Bp[(size_t)(k0 + kt + k)*ldb + (n0g + n)];
            }
        }
        __syncthreads();
        #pragma unroll
        for (int k=0;k<KT;++k){
            float4 av = *(const float4*)(&As[k][4*mt]);
            float4 bv = *(const float4*)(&Bs[k][4*nt]);
            acc[0][0]+=av.x*bv.x; acc[0][1]+=av.x*bv.y; acc[0][2]+=av.x*bv.z; acc[0][3]+=av.x*bv.w;
            acc[1][0]+=av.y*bv.x; acc[1][1]+=av.y*bv.y; acc[1][2]+=av.y*bv.z; acc[1][3]+=av.y*bv.w;
            acc[2][0]+=av.z*bv.x; acc[2][1]+=av.z*bv.y; acc[2][2]+=av.z*bv.z; acc[2][3]+=av.z*bv.w;
            acc[3][0]+=av.w*bv.x; acc[3][1]+=av.w*bv.y; acc[3][2]+=av.w*bv.z; acc[3][3]+=av.w*bv.w;
        }
    }
    #pragma unroll
    for (int i=0;i<4;++i){
        int gm = m0g + 4*mt + i;
        #pragma unroll
        for (int j=0;j<4;++j){
            int gn = n0g + 4*nt + j;
            float v = acc[i][j];
            if (bias) v += bias[gn];
            C[(size_t)gm*ldc + gn] = v;
        }
    }
}

// =====================================================================
// bf16 MFMA GEMM, M=32 x N=128 tile, KT=32, 256 thr (4 waves),
// double-buffered LDS. A fp32 via 8B agent loads (IF$-coherent);
// B bf16 (N,K) via normal cached loads (read-only weights, L2-resident).
// B tile: 2 threads/row, each thread loads 2x u16x8 (16 elems) -> full
// 128x32 coverage  [R6 bug: single u16x8 = half tile -> NaN].
// =====================================================================
#define ASTR 40
__device__ __forceinline__ void ldA4(const float* __restrict__ A1,int lda1,int ksplit,
                                     const float* __restrict__ A2,int lda2,
                                     int gk,int gm,
                                     unsigned long long& u0, unsigned long long& u1)
{
    const float* src = (gk < ksplit) ? (A1 + (size_t)gm*lda1 + gk)
                                     : (A2 + (size_t)gm*lda2 + (gk - ksplit));
    u0 = AG_LD((const unsigned long long*)src);
    u1 = AG_LD((const unsigned long long*)(src + 2));
}
__device__ __forceinline__ void stA4(unsigned short* dst,
                                     unsigned long long u0, unsigned long long u1)
{
    union { unsigned long long u; float f[2]; } a, b; a.u = u0; b.u = u1;
    ushort4 v; v.x=f2bf(a.f[0]); v.y=f2bf(a.f[1]); v.z=f2bf(b.f[0]); v.w=f2bf(b.f[1]);
    *(ushort4*)dst = v;
}

__device__ void gemm32(const float* __restrict__ A1,int lda1,int ksplit,
                       const float* __restrict__ A2,int lda2,
                       const unsigned short* __restrict__ B,int ldb,
                       const float* __restrict__ bias,
                       float* __restrict__ C,int ldc,
                       int K,int k0,int m0g,int n0g)
{
    __shared__ __align__(16) unsigned short As[2][32*ASTR];
    __shared__ __align__(16) unsigned short Bs[2][128*ASTR];
    const int tid=threadIdx.x, lane=tid&63, w=tid>>6;
    const int wn=w*32, fr=lane&15, koff=(lane>>4)*8;
    const int ar=tid>>3, akc=(tid&7)*4;     // A: 32 rows x 32k, 4 floats/thr
    const int br=tid>>1, bkc=(tid&1)*16;    // B: 128 rows x 32k, 16 bf16/thr (2x u16x8)

    f32x4 acc[2][2];
    acc[0][0]=acc[0][1]=acc[1][0]=acc[1][1]=(f32x4){0.f,0.f,0.f,0.f};

    const int NK = K >> 5;
    unsigned long long u0,u1; u16x8 bv0, bv1;
    {
        ldA4(A1,lda1,ksplit,A2,lda2, k0+akc, m0g+ar, u0,u1);
        const unsigned short* bp = B + (size_t)(n0g+br)*ldb + (k0+bkc);
        bv0 = *(const u16x8*)bp;
        bv1 = *(const u16x8*)(bp + 8);
    }
    stA4(&As[0][ar*ASTR+akc], u0,u1);
    *(u16x8*)&Bs[0][br*ASTR+bkc]     = bv0;
    *(u16x8*)&Bs[0][br*ASTR+bkc+8]   = bv1;
    __syncthreads();

    for (int kt=0; kt<NK; ++kt){
        const int cur = kt&1, nxt = cur^1;
        if (kt+1 < NK){
            int kk2 = k0 + (kt+1)*32;
            ldA4(A1,lda1,ksplit,A2,lda2, kk2+akc, m0g+ar, u0,u1);
            const unsigned short* bp = B + (size_t)(n0g+br)*ldb + (kk2+bkc);
            bv0 = *(const u16x8*)bp;
            bv1 = *(const u16x8*)(bp + 8);
        }
        s16x8 a0=*(const s16x8*)&As[cur][fr*ASTR+koff];
        s16x8 a1=*(const s16x8*)&As[cur][(16+fr)*ASTR+koff];
        s16x8 b0=*(const s16x8*)&Bs[cur][(wn+fr)*ASTR+koff];
        s16x8 b1=*(const s16x8*)&Bs[cur][(wn+16+fr)*ASTR+koff];
        acc[0][0]=__builtin_amdgcn_mfma_f32_16x16x32_bf16(a0,b0,acc[0][0],0,0,0);
        acc[0][1]=__builtin_amdgcn_mfma_f32_16x16x32_bf16(a0,b1,acc[0][1],0,0,0);
        acc[1][0]=__builtin_amdgcn_mfma_f32_16x16x32_bf16(a1,b0,acc[1][0],0,0,0);
        acc[1][1]=__builtin_amdgcn_mfma_f32_16x16x32_bf16(a1,b1,acc[1][1],0,0,0);
        if (kt+1 < NK){
            stA4(&As[nxt][ar*ASTR+akc], u0,u1);
            *(u16x8*)&Bs[nxt][br*ASTR+bkc]   = bv0;
            *(u16x8*)&Bs[nxt][br*ASTR+bkc+8] = bv1;
            __syncthreads();
        }
    }
    #pragma unroll
    for (int i=0;i<2;++i){
        #pragma unroll
        for (int j=0;j<2;++j){
            int gn = n0g + wn + j*16 + fr;
            float bb = bias ? bias[gn] : 0.f;
            #pragma unroll
            for (int r=0;r<4;++r){
                int gm = m0g + i*16 + (lane>>4)*4 + r;
                AG_ST(&C[(size_t)gm*ldc + gn], acc[i][j][r] + bb);
            }
        }
    }
}

// =====================================================================
// prep kernels
// =====================================================================
__global__ __launch_bounds__(256) void k_prep_convert(
    const float* __restrict__ hyp_Wx, const float* __restrict__ hyp_Wh,
    const float* __restrict__ hyp_bx, const float* __restrict__ hyp_bh,
    const float* __restrict__ Wx, const float* __restrict__ Wh,
    unsigned short* __restrict__ wcat1bf, unsigned short* __restrict__ wxbf,
    unsigned short* __restrict__ whbf, float* __restrict__ bias1,
    float* __restrict__ act1, float* __restrict__ c, float* __restrict__ ch,
    int* __restrict__ barrier_mem)
{
    size_t i = (size_t)blockIdx.x*256 + threadIdx.x;
    if (i < 1572864u) {   // Wcat1 = [hyp_Wx | hyp_Wh], (1024,1536)
        int n = (int)(i / 1536), k = (int)(i % 1536);
        float v = (k < 1280) ? hyp_Wx[(size_t)n*1280 + k] : hyp_Wh[(size_t)n*256 + (k-1280)];
        wcat1bf[i] = f2bf(v); return;
    }
    i -= 1572864u;
    if (i < 1048576u) { wxbf[i] = f2bf(Wx[i]); return; }
    i -= 1048576u;
    if (i < 4194304u) { whbf[i] = f2bf(Wh[i]); return; }
    i -= 4194304u;
    if (i < 1024u) { bias1[i] = hyp_bx[i] + hyp_bh[i]; return; }
    i -= 1024u;
    if (i < 163840u) { act1[i] = 0.f; return; }
    i -= 163840u;
    if (i < 131072u) { c[i] = 0.f; return; }
    i -= 131072u;
    if (i < 32768u) { ch[i] = 0.f; return; }
    i -= 32768u;
    if (i < 576u) { barrier_mem[i] = 0; return; }
}

__global__ __launch_bounds__(128) void k_prep_wcomb(
    const float* __restrict__ zw_w, const float* __restrict__ zb,
    const float* __restrict__ alpha, const float* __restrict__ zbeta,
    float* __restrict__ wcombf32)
{
    int kk = blockIdx.z;
    const float* A = (kk < 8) ? (zw_w + (size_t)kk*65536) : (zb + (size_t)(kk-8)*65536);
    const float* Bm = (kk < 8) ? (alpha + (size_t)kk*262144) : (zbeta + (size_t)(kk-8)*262144);
    gemm_dev(A, 256, KSPLIT_NONE, A, 256, Bm, 1024, 0, nullptr,
             wcombf32 + (size_t)kk*262144, 1024, 256, 0, blockIdx.x, blockIdx.y);
}

__global__ __launch_bounds__(256) void k_prep_cvtcomb(
    const float* __restrict__ wcombf32, unsigned short* __restrict__ wcombbf)
{
    size_t i = (size_t)blockIdx.x*256 + threadIdx.x;
    if (i >= 3145728u) return;
    int kk = (int)(i / 262144u);
    int r  = (int)(i % 262144u);
    int n = r / 256, k = r % 256;
    wcombbf[i] = f2bf(wcombf32[(size_t)kk*262144 + (size_t)k*1024 + n]);
}

__global__ __launch_bounds__(256) void k_prep_bcomb(
    const float* __restrict__ zw_b, const float* __restrict__ alpha,
    float* __restrict__ bcomb)
{
    int k = blockIdx.x;
    int n = blockIdx.y*256 + threadIdx.x;
    float s = 0.f;
    for (int p=0;p<256;++p)
        s += zw_b[k*256+p] * alpha[(size_t)k*262144 + (size_t)p*1024 + n];
    bcomb[(size_t)k*1024 + n] = s;
}

// =====================================================================
// params
// =====================================================================
struct Params {
    const float *x;
    const float *bias4, *lna_g, *lna_b, *ln_g, *ln_b;
    const float *hlna_g, *hlna_b, *hln_g, *hln_b;
    const float *fcW, *fcb;
    const unsigned short *wcat1bf, *wxbf, *whbf, *wcombbf;
    const float *bcomb, *bias1;
    float *act1, *c, *ch, *gpart, *scb, *xghg;
    int *arrive, *release;
    float *out;
};

// =====================================================================
// grid barrier over 512 blocks: distributed arrival stores (no RMW
// contention), block-0 parallel scan, single release word. Relaxed
// agent-scope atomics only. All 512 blocks resident (2/CU), so the
// spin-wait is deadlock-free.
// =====================================================================
__device__ __forceinline__ void gbar(const Params& p, int bid, int gen)
{
    __syncthreads();
    if (threadIdx.x == 0) {
        asm volatile("s_waitcnt vmcnt(0)" ::: "memory");
        AG_ST(&p.arrive[bid], gen);
    }
    if (bid == 0) {
        int ok;
        do {
            ok = (AG_LD(&p.arrive[threadIdx.x]) >= gen) &&
                 (AG_LD(&p.arrive[threadIdx.x + 256]) >= gen);
        } while (__syncthreads_count(ok) < 256);
        if (threadIdx.x == 0) AG_ST(&p.release[0], gen);
    } else {
        if (threadIdx.x == 0) {
            while (AG_LD(&p.release[0]) < gen)
                __builtin_amdgcn_s_sleep(8);
        }
    }
    __syncthreads();
}

// =====================================================================
// pointwise cell device functions (agent loads/stores on intermediates)
// =====================================================================
__device__ __forceinline__ void breduce2(float& a, float& b, volatile float* buf, int tid){
    #pragma unroll
    for (int off = 32; off > 0; off >>= 1) { a += __shfl_xor(a, off); b += __shfl_xor(b, off); }
    __syncthreads();
    if ((tid & 63) == 0) { buf[(tid>>6)*2] = a; buf[(tid>>6)*2+1] = b; }
    __syncthreads();
    a = buf[0] + buf[2] + buf[4] + buf[6];
    b = buf[1] + buf[3] + buf[5] + buf[7];
}

__device__ void hyper_cell_dev(int b, const Params& p)
{
    __shared__ float buf[8];
    int tid = threadIdx.x;
    float v[4];
    #pragma unroll
    for (int g=0; g<4; ++g){
        int idx = b*1024 + g*256 + tid;
        v[g] = AG_LD(&p.gpart[idx]) + AG_LD(&p.gpart[131072 + idx])
             + AG_LD(&p.gpart[262144 + idx]) + AG_LD(&p.gpart[393216 + idx]);
        // bias1 folded into partial 0 by the GEMM epilogue
    }
    #pragma unroll
    for (int g=0; g<4; ++g){
        float s = v[g], ss = v[g]*v[g];
        breduce2(s, ss, buf, tid);
        float m = s * (1.f/256.f);
        float var = ss * (1.f/256.f) - m*m;
        v[g] = (v[g]-m)*rsqrtf(var + EPS)*p.hlna_g[g*256+tid] + p.hlna_b[g*256+tid];
    }
    float chp = AG_LD(&p.ch[b*256 + tid]);
    float cn = sigm(v[1])*chp + sigm(v[0])*tanhf(v[2]);
    float s = cn, ss = cn*cn;
    breduce2(s, ss, buf, tid);
    float m = s*(1.f/256.f);
    float var = ss*(1.f/256.f) - m*m;
    float hn = sigm(v[3]) * tanhf((cn-m)*rsqrtf(var + EPS)*p.hln_g[tid] + p.hln_b[tid]);
    AG_ST(&p.ch[b*256 + tid], cn);
    AG_ST(&p.act1[b*1280 + 1024 + tid], hn);
}

__device__ void main_cell_dev(int b, const Params& p)
{
    __shared__ float buf[8];
    int tid = threadIdx.x;
    float gn[4][4];
    #pragma unroll
    for (int k=0;k<4;++k){
        float pre[4]; float s=0.f, ss=0.f;
        #pragma unroll
        for (int j=0;j<4;++j){
            int h = j*256 + tid;
            int n = k*1024 + h;
            int bh = b*1024 + h;
            float xgv = AG_LD(&p.xghg[b*4096 + n]);
            float hgv = AG_LD(&p.xghg[524288 + b*4096 + n])
                      + AG_LD(&p.xghg[1048576 + b*4096 + n]);   // hg splitK2 partials
            float pr = AG_LD(&p.scb[k*131072 + bh])*xgv + AG_LD(&p.scb[(4+k)*131072 + bh])*hgv
                     + p.bias4[n] + AG_LD(&p.scb[(8+k)*131072 + bh]);
            pre[j] = pr; s += pr; ss += pr*pr;
        }
        breduce2(s, ss, buf, tid);
        float m = s*(1.f/1024.f);
        float var = ss*(1.f/1024.f) - m*m;
        float rs = rsqrtf(var + EPS);
        #pragma unroll
        for (int j=0;j<4;++j){
            int h=j*256+tid, n=k*1024+h;
            gn[k][j] = (pre[j]-m)*rs*p.lna_g[n] + p.lna_b[n];
        }
    }
    float cnv[4]; float s=0.f, ss=0.f;
    #pragma unroll
    for (int j=0;j<4;++j){
        int h=j*256+tid;
        float cv = AG_LD(&p.c[b*1024+h]);
        float xv = sigm(gn[2][j])*cv + sigm(gn[0][j])*tanhf(gn[1][j]);
        cnv[j]=xv; s+=xv; ss+=xv*xv;
    }
    breduce2(s, ss, buf, tid);
    float m=s*(1.f/1024.f);
    float var=ss*(1.f/1024.f)-m*m;
    float rs=rsqrtf(var + EPS);
    #pragma unroll
    for (int j=0;j<4;++j){
        int h=j*256+tid;
        float hv = sigm(gn[3][j])*tanhf((cnv[j]-m)*rs*p.ln_g[h] + p.ln_b[h]);
        AG_ST(&p.c[b*1024+h], cnv[j]);
        AG_ST(&p.act1[b*1280 + h], hv);
    }
}

__device__ void fc_dev(int b, const Params& p)
{
    __shared__ float hs[1024];
    int tid = threadIdx.x;
    for (int i=tid; i<1024; i+=256) hs[i] = AG_LD(&p.act1[(size_t)b*1280 + i]);
    __syncthreads();
    if (tid < OUTN) {
        float s = p.fcb[tid];
        const float* wrow = p.fcW + (size_t)tid*1024;
        for (int k=0;k<1024;++k) s += hs[k]*wrow[k];
        p.out[b*OUTN + tid] = s;
    }
}

// =====================================================================
// persistent kernel: single pool of 512 blocks, 4 lean grid barriers
// per step. Static XCD-swizzled job map (xcd = bid&7) keeps each XCD's
// weight slice (~2.5 MB) resident in its 4 MB L2 across all steps.
// =====================================================================
__global__ __launch_bounds__(256, 2) void k_persist(Params p)
{
    const int bid = blockIdx.x;
    const int xcd = bid & 7, slot = bid >> 3;   // slot 0..63
    int gen = 1;

    for (int t = 0; t < T_STEPS; ++t) {
        const float* xt = p.x + (size_t)t*BATCH*DIN;

        // ---- phase A: 512 jobs, exactly one per block ----
        if (slot < 32) {                 // hg splitK2: 256 jobs, K=512
            int sidx = slot >> 2, mt = slot & 3;
            int slice = xcd + 8*sidx;    // 0..63 = (sp, nt)
            int sp = slice >> 5, nt = slice & 31;
            gemm32(p.act1, 1280, KSPLIT_NONE, p.act1, 1280,
                   p.whbf, 1024, nullptr,
                   p.xghg + 524288 + (size_t)sp*524288, 4096,
                   512, sp*512, mt*32, nt*128);
        } else if (slot < 48) {          // hyper gates splitK4: 128 jobs, K=384
            int q = slot - 32, sidx = q >> 2, mt = q & 3;
            int slice = xcd + 8*sidx;    // 0..31 = (sp, nt)
            int sp = slice >> 3, nt = slice & 7;
            gemm32(xt, 256, 256, p.act1, 1280,
                   p.wcat1bf, 1536, sp ? nullptr : p.bias1,
                   p.gpart + (size_t)sp*131072, 1024,
                   384, sp*384, mt*32, nt*128);
        } else {                         // xg: 128 jobs, K=256
            int q = slot - 48, sidx = q >> 2, mt = q & 3;
            int nt = xcd + 8*sidx;       // 0..31
            gemm32(xt, 256, KSPLIT_NONE, xt, 256,
                   p.wxbf, 256, nullptr,
                   p.xghg, 4096, 256, 0, mt*32, nt*128);
        }
        gbar(p, bid, gen++);

        // ---- phase B: hyper cell (128 rows on blocks 0..127) ----
        if (bid < 128) hyper_cell_dev(bid, p);
        gbar(p, bid, gen++);

        // ---- phase C: 12 sc GEMMs = 384 jobs on blocks 0..383 ----
        if (slot < 48) {
            int sidx = slot >> 2, mt = slot & 3;
            int slice = xcd + 8*sidx;    // 0..95 = (kk, nt)
            int kk = slice >> 3, nt = slice & 7;
            gemm32(p.act1 + 1024, 1280, KSPLIT_NONE, p.act1 + 1024, 1280,
                   p.wcombbf + (size_t)kk*262144, 256,
                   kk < 8 ? p.bcomb + (size_t)kk*1024 : nullptr,
                   p.scb + (size_t)kk*131072, 1024,
                   256, 0, mt*32, nt*128);
        }
        gbar(p, bid, gen++);

        // ---- phase D: main cell (128 rows on blocks 0..127) ----
        if (bid < 128) main_cell_dev(bid, p);
        gbar(p, bid, gen++);
    }

    // ---- final FC ----
    if (bid < 128) fc_dev(bid, p);
}

// =====================================================================
// launch
// =====================================================================
extern "C" void kernel_launch(void* const* d_in, const int* in_sizes, int n_in,
                              void* d_out, int out_size, void* d_ws, size_t ws_size,
                              hipStream_t stream)
{
    const float* x        = (const float*)d_in[0];
    const float* Wx       = (const float*)d_in[1];
    const float* Wh       = (const float*)d_in[2];
    const float* bias     = (const float*)d_in[3];
    const float* lna_g    = (const float*)d_in[4];
    const float* lna_b    = (const float*)d_in[5];
    const float* ln_g     = (const float*)d_in[6];
    const float* ln_b     = (const float*)d_in[7];
    const float* zb       = (const float*)d_in[8];
    const float* zbeta    = (const float*)d_in[9];
    const float* zw_w     = (const float*)d_in[10];
    const float* zw_b     = (const float*)d_in[11];
    const float* alpha    = (const float*)d_in[12];
    const float* hyp_Wx   = (const float*)d_in[13];
    const float* hyp_bx   = (const float*)d_in[14];
    const float* hyp_Wh   = (const float*)d_in[15];
    const float* hyp_bh   = (const float*)d_in[16];
    const float* hlna_g   = (const float*)d_in[17];
    const float* hlna_b   = (const float*)d_in[18];
    const float* hln_g    = (const float*)d_in[19];
    const float* hln_b    = (const float*)d_in[20];
    const float* fcW      = (const float*)d_in[21];
    const float* fcb      = (const float*)d_in[22];

    // ---- workspace carve-up ----
    unsigned short* wcat1bf = (unsigned short*)d_ws;          // 1,572,864
    unsigned short* wxbf    = wcat1bf + 1572864;              // 1,048,576
    unsigned short* whbf    = wxbf + 1048576;                 // 4,194,304
    unsigned short* wcombbf = whbf + 4194304;                 // 3,145,728
    float* bcomb = (float*)(wcombbf + 3145728);               // 8,192
    float* bias1 = bcomb + 8192;                              // 1,024
    float* act1  = bias1 + 1024;                              // 163,840  [h|hh]
    float* c     = act1 + 163840;                             // 131,072
    float* ch    = c + 131072;                                // 32,768
    float* stepbuf = ch + 32768;                              // 3,670,016 floats
    float* gpart = stepbuf;                                   // 4 x 131,072 (hyper splitK4)
    float* scb   = gpart + 524288;                            // 12 x 131,072
    float* xghg  = scb + 1572864;                             // xg + hg0 + hg1 (3 x 524,288)
    float* wcombf32 = stepbuf;                                // prep-time alias
    int* barrier_mem = (int*)(stepbuf + 3670016);             // 576 ints

    // ---- prep ----
    k_prep_convert<<<(7145024 + 255)/256, 256, 0, stream>>>(
        hyp_Wx, hyp_Wh, hyp_bx, hyp_bh, Wx, Wh,
        wcat1bf, wxbf, whbf, bias1, act1, c, ch, barrier_mem);
    k_prep_wcomb<<<dim3(8,16,12), 128, 0, stream>>>(zw_w, zb, alpha, zbeta, wcombf32);
    k_prep_bcomb<<<dim3(8,4), 256, 0, stream>>>(zw_b, alpha, bcomb);
    k_prep_cvtcomb<<<(3145728 + 255)/256, 256, 0, stream>>>(wcombf32, wcombbf);

    // ---- persistent kernel: entire 512-step scan + FC ----
    Params p;
    p.x = x; p.bias4 = bias;
    p.lna_g = lna_g; p.lna_b = lna_b; p.ln_g = ln_g; p.ln_b = ln_b;
    p.hlna_g = hlna_g; p.hlna_b = hlna_b; p.hln_g = hln_g; p.hln_b = hln_b;
    p.fcW = fcW; p.fcb = fcb;
    p.wcat1bf = wcat1bf; p.wxbf = wxbf; p.whbf = whbf; p.wcombbf = wcombbf;
    p.bcomb = bcomb; p.bias1 = bias1;
    p.act1 = act1; p.c = c; p.ch = ch;
    p.gpart = gpart; p.scb = scb; p.xghg = xghg;
    p.arrive = barrier_mem; p.release = barrier_mem + 544;
    p.out = (float*)d_out;

    k_persist<<<512, 256, 0, stream>>>(p);
}